// Round 3
// baseline (77.803 us; speedup 1.0000x reference)
//
#include <hip/hip_runtime.h>

// Problem constants (fixed by the harness: B=4096, K=128, C=64)
#define K_KP   128
#define C_COMP 64
#define NPAIR  (C_COMP / 2)   // 32 c-pairs per k
#define RECF   12             // floats per c-pair record (48 B, 16B-aligned)
#define KPB    4              // k's per block (one per wave)

typedef float v2f __attribute__((ext_vector_type(2)));

#if __has_builtin(__builtin_amdgcn_exp2f)
#define EXP2F(x) __builtin_amdgcn_exp2f(x)
#else
#define EXP2F(x) exp2f(x)
#endif
#if __has_builtin(__builtin_amdgcn_logf)
#define LOG2F_(x) __builtin_amdgcn_logf(x)
#else
#define LOG2F_(x) __log2f(x)
#endif
#if __has_builtin(__builtin_amdgcn_rcpf)
#define RCPF(x) __builtin_amdgcn_rcpf(x)
#else
#define RCPF(x) (1.0f/(x))
#endif
#if __has_builtin(__builtin_amdgcn_rsqf)
#define RSQF(x) __builtin_amdgcn_rsqf(x)
#else
#define RSQF(x) rsqrtf(x)
#endif

// broadcast lane l's value of v to all lanes (lands in an SGPR) — fallback path
__device__ __forceinline__ float rlane(float v, int l) {
    union { float f; int i; } u; u.f = v;
    u.i = __builtin_amdgcn_readlane(u.i, l);
    return u.f;
}

// per-component eval on a v2f pair of b-values; constants are wave-uniform
// (SGPR), each VALU op reads at most 1 SGPR. Relies on -ffp-contract.
#define EVAL(m0, m1, i00, i01, i11, lc)                                 \
    {                                                                   \
        v2f d0 = ZX - (m0);                                             \
        v2f d1 = ZY - (m1);                                             \
        v2f s0 = (i00) * d0 + (i01) * d1;  /* k2 * (Sigma^-1 diff)_0 */ \
        v2f s1 = (i01) * d0 + (i11) * d1;                               \
        v2f arg = (lc) - d0 * s0 - d1 * s1; /* lc - k2*maha */          \
        v2f e;                                                          \
        e.x = EXP2F(arg.x);                                             \
        e.y = EXP2F(arg.y);                                             \
        pdf += e;                                                       \
        G0  += e * s0;                                                  \
        G1  += e * s1;                                                  \
    }

// shared epilogue: pdf/G0/G1 -> two float2 stores
#define EPILOGUE()                                                            \
    {                                                                         \
        float2 sc = ((const float2*)scale)[k];                                \
        const float NEG_INV_K2 = -1.3862943611f; /* -1/K2 = -2 ln 2 */        \
        float f0 = sc.x * NEG_INV_K2;                                         \
        float f1 = sc.y * NEG_INV_K2;                                         \
        const int KK2 = 2 * K_KP;                                             \
        float* out0 = out;                                                    \
        float* out1 = out + (size_t)B * KK2;                                  \
        float pdfj[2] = {pdf.x, pdf.y};                                       \
        float gs0j[2] = {G0.x, G0.y};                                         \
        float gs1j[2] = {G1.x, G1.y};                                         \
        _Pragma("unroll")                                                     \
        for (int j = 0; j < 2; ++j) {                                         \
            int b = b0 + lane + j * 64;                                       \
            float x  = 2.0f * pdfj[j] - 1.0f; /* sigmoid((pdf-0.5)/0.5) */    \
            float ex = EXP2F(-1.44269504f * x);                               \
            float dn = RCPF(1.0f + ex);                                       \
            float g0 = gs0j[j] * f0;                                          \
            float g1 = gs1j[j] * f1;                                          \
            float n2 = fmaf(g0, g0, g1 * g1);                                 \
            float rn = RSQF(n2);                                              \
            float nrm = n2 * rn;                                              \
            float mag = EXP2F(fmaf(nrm, -0.0013115409f, 7.2134752044f));      \
            float mm = rn * mag;                                              \
            ((float2*)(out0 + (size_t)b * KK2 + 2 * k))[0] =                  \
                make_float2(dn, dn);                                          \
            ((float2*)(out1 + (size_t)b * KK2 + 2 * k))[0] =                  \
                make_float2(g0 * mm, g1 * mm);                                \
        }                                                                     \
    }

// ---------------- prep: derive per-(k,c) params into d_ws ----------------
// record per c-pair p (12 floats = 48B):
//   [0..3] m0,m1,i00,i01 (c=2p)  [4..7] same (c=2p+1)  [8..11] i11,lc,i11,lc
__global__ __launch_bounds__(256) void prep_kernel(
    const float* __restrict__ weights,  // [K,C]
    const float* __restrict__ means,    // [K,C,2]
    const float* __restrict__ covs,     // [K,C,2,2]
    float* __restrict__ params)
{
    const float K2       = 0.72134752044f;   // 0.5 * log2(e)
    const float LOG2_2PI = 2.6514961295f;    // log2(2*pi)
    int g = blockIdx.x * 256 + threadIdx.x;  // g = k*64 + c
    int k = g >> 6, c = g & 63;
    float  w  = weights[g];
    float2 m  = ((const float2*)means)[g];
    float4 cv = ((const float4*)covs)[g];    // a, b, c, d
    float det  = cv.x * cv.w - cv.y * cv.z;
    float rdet = RCPF(det);
    float i00 =  cv.w * rdet * K2;
    float i01 = -cv.y * rdet * K2;
    float i11 =  cv.x * rdet * K2;
    float lc  = LOG2F_(w) - LOG2_2PI - 0.5f * LOG2F_(det);
    float* rec = params + ((size_t)k * NPAIR + (c >> 1)) * RECF;
    ((float4*)rec)[c & 1] = make_float4(m.x, m.y, i00, i01);
    ((float2*)(rec + 8))[c & 1] = make_float2(i11, lc);
}

// ---------------- main: wave-uniform k, params via scalar loads ----------
// 256 threads = 4 waves, each wave owns ONE k. kp is wave-uniform ->
// compiler selects s_load_dwordx4 (constant cache): constants stream on the
// scalar pipe, zero VALU/DS/readlane cost in the loop.
// Grid = (K/4)*(B/128) = 1024 -> 4 blocks/CU, 16 waves/CU.
__global__ __launch_bounds__(256, 4) void recovery_kernel(
    const float* __restrict__ z,       // [B,K,2]
    const float* __restrict__ params,  // [K, NPAIR, 12] derived
    const float* __restrict__ scale,   // [K,2]
    float* __restrict__ out, int B)
{
    const int t    = threadIdx.x;
    const int lane = t & 63;
    const int wv   = __builtin_amdgcn_readfirstlane(t >> 6);
    // XCD-bijective swizzle (1024 % 8 == 0): all 32 kb-blocks of one bb land
    // on one XCD -> shared z lines / out lines merge in one L2.
    const int bid = blockIdx.x;
    const int swz = (bid & 7) * 128 + (bid >> 3);
    const int kb  = swz & 31;
    const int bb  = swz >> 5;
    const int k   = kb * KPB + wv;            // wave-uniform
    const int b0  = bb * 128;

    const float2* z2 = (const float2*)z;
    float2 za = z2[(size_t)(b0 + lane)      * K_KP + k];
    float2 zb = z2[(size_t)(b0 + lane + 64) * K_KP + k];
    v2f ZX = {za.x, zb.x};
    v2f ZY = {za.y, zb.y};
    v2f pdf = {0.f, 0.f}, G0 = {0.f, 0.f}, G1 = {0.f, 0.f};

    const float* __restrict__ kp = params + (size_t)k * (NPAIR * RECF);
#pragma unroll
    for (int p = 0; p < NPAIR; ++p) {
        float4 A0 = *(const float4*)(kp + p * RECF);      // m0,m1,i00,i01 (2p)
        float4 A1 = *(const float4*)(kp + p * RECF + 4);  // m0,m1,i00,i01 (2p+1)
        float4 Bp = *(const float4*)(kp + p * RECF + 8);  // i11,lc (2p), i11,lc (2p+1)
        EVAL(A0.x, A0.y, A0.z, A0.w, Bp.x, Bp.y);
        EVAL(A1.x, A1.y, A1.z, A1.w, Bp.z, Bp.w);
    }
    EPILOGUE();
}

// ---------------- fallback (no workspace): round-2 readlane version -------
__global__ __launch_bounds__(256, 4) void recovery_kernel_rl(
    const float* __restrict__ z,
    const float* __restrict__ weights,
    const float* __restrict__ means,
    const float* __restrict__ covs,
    const float* __restrict__ scale,
    float* __restrict__ out, int B)
{
    const int t    = threadIdx.x;
    const int lane = t & 63;
    const int wv   = __builtin_amdgcn_readfirstlane(t >> 6);
    const int bid = blockIdx.x;
    const int swz = (bid & 7) * 128 + (bid >> 3);
    const int kb  = swz & 31;
    const int bb  = swz >> 5;
    const int k   = kb * KPB + wv;
    const int b0  = bb * 128;

    const float K2       = 0.72134752044f;
    const float LOG2_2PI = 2.6514961295f;
    const int g = k * C_COMP + lane;
    float  w  = weights[g];
    float2 m  = ((const float2*)means)[g];
    float4 cv = ((const float4*)covs)[g];
    float det  = cv.x * cv.w - cv.y * cv.z;
    float rdet = RCPF(det);
    float vm0  = m.x;
    float vm1  = m.y;
    float vi00 =  cv.w * rdet * K2;
    float vi01 = -cv.y * rdet * K2;
    float vi11 =  cv.x * rdet * K2;
    float vlc  = LOG2F_(w) - LOG2_2PI - 0.5f * LOG2F_(det);

    const float2* z2 = (const float2*)z;
    float2 za = z2[(size_t)(b0 + lane)      * K_KP + k];
    float2 zb = z2[(size_t)(b0 + lane + 64) * K_KP + k];
    v2f ZX = {za.x, zb.x};
    v2f ZY = {za.y, zb.y};
    v2f pdf = {0.f, 0.f}, G0 = {0.f, 0.f}, G1 = {0.f, 0.f};

#pragma unroll
    for (int c = 0; c < C_COMP; ++c) {
        float m0  = rlane(vm0, c);
        float m1  = rlane(vm1, c);
        float i00 = rlane(vi00, c);
        float i01 = rlane(vi01, c);
        float i11 = rlane(vi11, c);
        float lc  = rlane(vlc, c);
        EVAL(m0, m1, i00, i01, i11, lc);
    }
    EPILOGUE();
}

extern "C" void kernel_launch(void* const* d_in, const int* in_sizes, int n_in,
                              void* d_out, int out_size, void* d_ws, size_t ws_size,
                              hipStream_t stream) {
    const float* z       = (const float*)d_in[0];
    const float* weights = (const float*)d_in[1];
    const float* means   = (const float*)d_in[2];
    const float* covs    = (const float*)d_in[3];
    const float* scale   = (const float*)d_in[4];
    float* out = (float*)d_out;

    int B = in_sizes[0] / (2 * K_KP);            // 4096
    int grid = (K_KP / KPB) * (B / 128);         // 1024

    const size_t PARAM_BYTES = (size_t)K_KP * NPAIR * RECF * sizeof(float); // 196,608
    if (d_ws && ws_size >= PARAM_BYTES) {
        float* params = (float*)d_ws;
        prep_kernel<<<(K_KP * C_COMP) / 256, 256, 0, stream>>>(weights, means, covs, params);
        recovery_kernel<<<grid, 256, 0, stream>>>(z, params, scale, out, B);
    } else {
        recovery_kernel_rl<<<grid, 256, 0, stream>>>(z, weights, means, covs, scale, out, B);
    }
}

// Round 4
// 75.985 us; speedup vs baseline: 1.0239x; 1.0239x over previous
//
#include <hip/hip_runtime.h>

// Problem constants (fixed by the harness: B=4096, K=128, C=64)
#define K_KP   128
#define C_COMP 64
#define TK     8       // k-columns per block
#define TBS    32      // b-slots per block (threads = TK*TBS = 256)
#define NB     8       // b values per thread -> block covers 256 b x 8 k
#define NG     (NB/2)  // v2f groups
#define LDS_STRIDE 388 // floats per k row: 32 c-pairs * 12 + 4 pad (388%32=4 -> 8 rows cover all banks)

typedef float v2f __attribute__((ext_vector_type(2)));

#if __has_builtin(__builtin_amdgcn_exp2f)
#define EXP2F(x) __builtin_amdgcn_exp2f(x)
#else
#define EXP2F(x) exp2f(x)
#endif
#if __has_builtin(__builtin_amdgcn_logf)
#define LOG2F_(x) __builtin_amdgcn_logf(x)
#else
#define LOG2F_(x) __log2f(x)
#endif
#if __has_builtin(__builtin_amdgcn_rcpf)
#define RCPF(x) __builtin_amdgcn_rcpf(x)
#else
#define RCPF(x) (1.0f/(x))
#endif
#if __has_builtin(__builtin_amdgcn_rsqf)
#define RSQF(x) __builtin_amdgcn_rsqf(x)
#else
#define RSQF(x) rsqrtf(x)
#endif

// per c-pair eval on a v2f pair of b-values; relies on -ffp-contract for pk_fma
#define EVAL(m0, m1, i00, i01, i11, lc, ZX, ZY, PDF, G0, G1)            \
    {                                                                   \
        v2f d0 = ZX - (m0);                                             \
        v2f d1 = ZY - (m1);                                             \
        v2f s0 = (i00) * d0 + (i01) * d1;  /* k2 * (Sigma^-1 diff)_0 */ \
        v2f s1 = (i01) * d0 + (i11) * d1;                               \
        v2f arg = (lc) - d0 * s0 - d1 * s1; /* lc - k2*maha */          \
        v2f e;                                                          \
        e.x = EXP2F(arg.x);                                             \
        e.y = EXP2F(arg.y);                                             \
        PDF += e;                                                       \
        G0 += e * s0;                                                   \
        G1 += e * s1;                                                   \
    }

// 256 threads (4 waves). Grid = (K/TK)*(B/(TBS*NB)) = 16*16 = 256 blocks ->
// exactly 1 block/CU; VGPRs unconstrained (1 wave/SIMD).
// NB=8 halves the DS-read count per output element vs NB=4 (the measured
// bottleneck pipe: 96 ds_read_b128/wave serve 8 b's instead of 4).
__global__ __launch_bounds__(256, 1) void recovery_kernel(
    const float* __restrict__ z,       // [B,K,2]
    const float* __restrict__ weights, // [K,C]
    const float* __restrict__ means,   // [K,C,2]
    const float* __restrict__ covs,    // [K,C,2,2]
    const float* __restrict__ scale,   // [K,2]
    float* __restrict__ out, int B)
{
    __shared__ float lds[TK * LDS_STRIDE];   // 12,416 B

    const int t  = threadIdx.x;
    const int kb = blockIdx.x & 15;          // K/TK = 16 k-blocks
    const int bb = blockIdx.x >> 4;          // B/256 = 16 b-blocks
    const int k0 = kb * TK;
    const int b0 = bb * (TBS * NB);          // 256 b per block

    const int kl = t & 7;
    const int bl = t >> 3;                   // 0..31
    const int kg = k0 + kl;

    // ---- issue this thread's NB z loads FIRST (cold HBM misses: the 268 MB
    // harness fill flushes all caches each iteration). Latency hides under
    // the staging phase below. Each wave-load covers 8 full 64B lines. ----
    const float2* z2 = (const float2*)z;     // [B*K]
    float zx[NB], zy[NB];
#pragma unroll
    for (int j = 0; j < NB; ++j) {
        int b = b0 + bl + j * TBS;
        float2 v = z2[(size_t)b * K_KP + kg];
        zx[j] = v.x; zy[j] = v.y;
    }

    // ---- stage per-(k,c) derived params into LDS ----
    // layout per k-row, per c-pair p (12 floats):
    //   [m0,m1,i00,i01]_{c=2p}  [m0,m1,i00,i01]_{c=2p+1}  [i11,lc]_{2p} [i11,lc]_{2p+1}
    const float K2       = 0.72134752044f;   // 0.5 * log2(e)
    const float LOG2_2PI = 2.6514961295f;    // log2(2*pi)
    for (int i = t; i < TK * C_COMP; i += 256) {
        int klr = i >> 6;                    // 0..7
        int c   = i & 63;
        int g   = (k0 + klr) * C_COMP + c;
        float w  = weights[g];
        float m0 = means[2*g], m1 = means[2*g + 1];
        float a  = covs[4*g],     bq = covs[4*g + 1];
        float cq = covs[4*g + 2], d  = covs[4*g + 3];
        float det  = a*d - bq*cq;
        float rdet = RCPF(det);
        float i00 = d  * rdet * K2;
        float i01 = -bq * rdet * K2;
        float i11 = a  * rdet * K2;
        float lc = LOG2F_(w) - LOG2_2PI - 0.5f * LOG2F_(det);
        float* row = &lds[klr * LDS_STRIDE + (c >> 1) * 12];
        ((float4*)(row + (c & 1) * 4))[0] = make_float4(m0, m1, i00, i01);
        ((float2*)(row + 8 + (c & 1) * 2))[0] = make_float2(i11, lc);
    }
    __syncthreads();

    v2f ZX[NG], ZY[NG], PDF[NG], G0[NG], G1[NG];
#pragma unroll
    for (int g = 0; g < NG; ++g) {
        ZX[g] = (v2f){zx[2*g], zx[2*g+1]};
        ZY[g] = (v2f){zy[2*g], zy[2*g+1]};
        PDF[g] = (v2f){0.f, 0.f};
        G0[g]  = (v2f){0.f, 0.f};
        G1[g]  = (v2f){0.f, 0.f};
    }

    const float* kp = &lds[kl * LDS_STRIDE];
#pragma unroll 2
    for (int p = 0; p < C_COMP / 2; ++p) {
        float4 A0 = *(const float4*)(kp + p * 12);
        float4 A1 = *(const float4*)(kp + p * 12 + 4);
        float4 Bp = *(const float4*)(kp + p * 12 + 8);
#pragma unroll
        for (int g = 0; g < NG; ++g) {
            EVAL(A0.x, A0.y, A0.z, A0.w, Bp.x, Bp.y, ZX[g], ZY[g], PDF[g], G0[g], G1[g]);
            EVAL(A1.x, A1.y, A1.z, A1.w, Bp.z, Bp.w, ZX[g], ZY[g], PDF[g], G0[g], G1[g]);
        }
    }

    // ---- epilogue ----
    float2 sc = ((const float2*)scale)[kg];
    const float NEG_INV_K2 = -1.3862943611f;     // -1/K2 = -2 ln 2
    float f0 = sc.x * NEG_INV_K2;                // fold unnorm scale + sign + 1/k2
    float f1 = sc.y * NEG_INV_K2;
    const int KK2 = 2 * K_KP;                    // 256
    float* out0 = out;
    float* out1 = out + (size_t)B * KK2;
#pragma unroll
    for (int j = 0; j < NB; ++j) {
        int g = j >> 1;
        float pdfj = (j & 1) ? PDF[g].y : PDF[g].x;
        float gs0j = (j & 1) ? G0[g].y  : G0[g].x;
        float gs1j = (j & 1) ? G1[g].y  : G1[g].x;
        int b = b0 + bl + j * TBS;
        // density_norm = sigmoid((pdf + eps)/tau) = sigmoid(2*pdf - 1)
        float x  = 2.0f * pdfj - 1.0f;
        float ex = EXP2F(-1.44269504f * x);
        float dn = RCPF(1.0f + ex);
        // gradient branch
        float g0 = gs0j * f0;                    // grad_raw
        float g1 = gs1j * f1;
        float n2 = fmaf(g0, g0, g1 * g1);
        float rn = RSQF(n2);
        float nrm = n2 * rn;                     // |grad_raw|
        // mag = exp((5500 - nrm)/1100) = exp2(7.2134752 - nrm*log2(e)/1100)
        float mag = EXP2F(fmaf(nrm, -0.0013115409f, 7.2134752044f));
        float m = rn * mag;
        ((float2*)(out0 + (size_t)b * KK2 + 2 * kg))[0] = make_float2(dn, dn);
        ((float2*)(out1 + (size_t)b * KK2 + 2 * kg))[0] = make_float2(g0 * m, g1 * m);
    }
}

extern "C" void kernel_launch(void* const* d_in, const int* in_sizes, int n_in,
                              void* d_out, int out_size, void* d_ws, size_t ws_size,
                              hipStream_t stream) {
    const float* z       = (const float*)d_in[0];
    const float* weights = (const float*)d_in[1];
    const float* means   = (const float*)d_in[2];
    const float* covs    = (const float*)d_in[3];
    const float* scale   = (const float*)d_in[4];
    float* out = (float*)d_out;

    int B = in_sizes[0] / (2 * K_KP);            // 4096
    int grid = (K_KP / TK) * (B / (TBS * NB));   // 16 * 16 = 256
    recovery_kernel<<<grid, 256, 0, stream>>>(z, weights, means, covs, scale, out, B);
}

// Round 5
// 74.514 us; speedup vs baseline: 1.0442x; 1.0197x over previous
//
#include <hip/hip_runtime.h>

// Problem constants (fixed by the harness: B=4096, K=128, C=64)
#define K_KP   128
#define C_COMP 64
#define TK     8       // k-columns per block
#define TBS    32      // b-slots per block (threads = TK*TBS = 256)
#define NB     4       // b values per thread -> block covers 128 b x 8 k
#define LDS_STRIDE 388 // floats per k row: 32 c-pairs * 12 + 4 pad (388%32=4 -> 8 rows cover all banks)

typedef float v2f __attribute__((ext_vector_type(2)));

#if __has_builtin(__builtin_amdgcn_exp2f)
#define EXP2F(x) __builtin_amdgcn_exp2f(x)
#else
#define EXP2F(x) exp2f(x)
#endif
#if __has_builtin(__builtin_amdgcn_logf)
#define LOG2F_(x) __builtin_amdgcn_logf(x)
#else
#define LOG2F_(x) __log2f(x)
#endif
#if __has_builtin(__builtin_amdgcn_rcpf)
#define RCPF(x) __builtin_amdgcn_rcpf(x)
#else
#define RCPF(x) (1.0f/(x))
#endif
#if __has_builtin(__builtin_amdgcn_rsqf)
#define RSQF(x) __builtin_amdgcn_rsqf(x)
#else
#define RSQF(x) rsqrtf(x)
#endif

// per c-pair eval on a v2f pair of b-values; relies on -ffp-contract for pk_fma
#define EVAL(m0, m1, i00, i01, i11, lc, ZX, ZY, PDF, G0, G1)            \
    {                                                                   \
        v2f d0 = ZX - (m0);                                             \
        v2f d1 = ZY - (m1);                                             \
        v2f s0 = (i00) * d0 + (i01) * d1;  /* k2 * (Sigma^-1 diff)_0 */ \
        v2f s1 = (i01) * d0 + (i11) * d1;                               \
        v2f arg = (lc) - d0 * s0 - d1 * s1; /* lc - k2*maha */          \
        v2f e;                                                          \
        e.x = EXP2F(arg.x);                                             \
        e.y = EXP2F(arg.y);                                             \
        PDF += e;                                                       \
        G0 += e * s0;                                                   \
        G1 += e * s1;                                                   \
    }

// 256 threads (4 waves). Grid = 512 -> 2 blocks/CU, 8 waves/CU.
// Measured-best structure (prev session 73.3 / R0 74.7).
__global__ __launch_bounds__(256, 4) void recovery_kernel(
    const float* __restrict__ z,       // [B,K,2]
    const float* __restrict__ weights, // [K,C]
    const float* __restrict__ means,   // [K,C,2]
    const float* __restrict__ covs,    // [K,C,2,2]
    const float* __restrict__ scale,   // [K,2]
    float* __restrict__ out, int B)
{
    __shared__ float lds[TK * LDS_STRIDE];   // 12,416 B

    const int t  = threadIdx.x;
    const int kb = blockIdx.x & 15;          // K/TK = 16 k-blocks
    const int bb = blockIdx.x >> 4;
    const int k0 = kb * TK;
    const int b0 = bb * (TBS * NB);          // 128 b per block

    const int kl = t & 7;
    const int bl = t >> 3;                   // 0..31
    const int kg = k0 + kl;

    // ---- issue this thread's NB z loads FIRST: cold HBM misses (caches are
    // flushed by the 268 MB harness fill each iteration) hide under the
    // param staging below instead of serializing after the barrier. ----
    const float2* z2 = (const float2*)z;     // [B*K]
    float zx[NB], zy[NB];
#pragma unroll
    for (int j = 0; j < NB; ++j) {
        int b = b0 + bl + j * TBS;
        float2 v = z2[(size_t)b * K_KP + kg];
        zx[j] = v.x; zy[j] = v.y;
    }

    // ---- stage per-(k,c) derived params into LDS ----
    // layout per k-row, per c-pair p (12 floats):
    //   [m0,m1,i00,i01]_{c=2p}  [m0,m1,i00,i01]_{c=2p+1}  [i11,lc]_{2p} [i11,lc]_{2p+1}
    const float K2       = 0.72134752044f;   // 0.5 * log2(e)
    const float LOG2_2PI = 2.6514961295f;    // log2(2*pi)
    for (int i = t; i < TK * C_COMP; i += 256) {
        int klr = i >> 6;                    // 0..7
        int c   = i & 63;
        int g   = (k0 + klr) * C_COMP + c;
        float w  = weights[g];
        float m0 = means[2*g], m1 = means[2*g + 1];
        float a  = covs[4*g],     bq = covs[4*g + 1];
        float cq = covs[4*g + 2], d  = covs[4*g + 3];
        float det  = a*d - bq*cq;
        float rdet = RCPF(det);
        float i00 = d  * rdet * K2;
        float i01 = -bq * rdet * K2;
        float i11 = a  * rdet * K2;
        float lc = LOG2F_(w) - LOG2_2PI - 0.5f * LOG2F_(det);
        float* row = &lds[klr * LDS_STRIDE + (c >> 1) * 12];
        ((float4*)(row + (c & 1) * 4))[0] = make_float4(m0, m1, i00, i01);
        ((float2*)(row + 8 + (c & 1) * 2))[0] = make_float2(i11, lc);
    }
    __syncthreads();

    v2f ZXa = {zx[0], zx[1]}, ZXb = {zx[2], zx[3]};
    v2f ZYa = {zy[0], zy[1]}, ZYb = {zy[2], zy[3]};
    v2f pdfa = {0.f, 0.f}, pdfb = {0.f, 0.f};
    v2f g0a  = {0.f, 0.f}, g0b  = {0.f, 0.f};
    v2f g1a  = {0.f, 0.f}, g1b  = {0.f, 0.f};

    const float* kp = &lds[kl * LDS_STRIDE];
#pragma unroll 4
    for (int p = 0; p < C_COMP / 2; ++p) {
        float4 A0 = *(const float4*)(kp + p * 12);
        float4 A1 = *(const float4*)(kp + p * 12 + 4);
        float4 Bp = *(const float4*)(kp + p * 12 + 8);
        EVAL(A0.x, A0.y, A0.z, A0.w, Bp.x, Bp.y, ZXa, ZYa, pdfa, g0a, g1a);
        EVAL(A0.x, A0.y, A0.z, A0.w, Bp.x, Bp.y, ZXb, ZYb, pdfb, g0b, g1b);
        EVAL(A1.x, A1.y, A1.z, A1.w, Bp.z, Bp.w, ZXa, ZYa, pdfa, g0a, g1a);
        EVAL(A1.x, A1.y, A1.z, A1.w, Bp.z, Bp.w, ZXb, ZYb, pdfb, g0b, g1b);
    }

    float pdf[NB] = {pdfa.x, pdfa.y, pdfb.x, pdfb.y};
    float gs0[NB] = {g0a.x, g0a.y, g0b.x, g0b.y};
    float gs1[NB] = {g1a.x, g1a.y, g1b.x, g1b.y};

    // ---- epilogue ----
    float2 sc = ((const float2*)scale)[kg];
    const float NEG_INV_K2 = -1.3862943611f;     // -1/K2 = -2 ln 2
    float f0 = sc.x * NEG_INV_K2;                // fold unnorm scale + sign + 1/k2
    float f1 = sc.y * NEG_INV_K2;
    const int KK2 = 2 * K_KP;                    // 256
    float* out0 = out;
    float* out1 = out + (size_t)B * KK2;
#pragma unroll
    for (int j = 0; j < NB; ++j) {
        int b = b0 + bl + j * TBS;
        // density_norm = sigmoid((pdf + eps)/tau) = sigmoid(2*pdf - 1)
        float x  = 2.0f * pdf[j] - 1.0f;
        float ex = EXP2F(-1.44269504f * x);
        float dn = RCPF(1.0f + ex);
        // gradient branch
        float g0 = gs0[j] * f0;                  // grad_raw
        float g1 = gs1[j] * f1;
        float n2 = fmaf(g0, g0, g1 * g1);
        float rn = RSQF(n2);
        float nrm = n2 * rn;                     // |grad_raw|
        // mag = exp((5500 - nrm)/1100) = exp2(7.2134752 - nrm*log2(e)/1100)
        float mag = EXP2F(fmaf(nrm, -0.0013115409f, 7.2134752044f));
        float m = rn * mag;
        ((float2*)(out0 + (size_t)b * KK2 + 2 * kg))[0] = make_float2(dn, dn);
        ((float2*)(out1 + (size_t)b * KK2 + 2 * kg))[0] = make_float2(g0 * m, g1 * m);
    }
}

extern "C" void kernel_launch(void* const* d_in, const int* in_sizes, int n_in,
                              void* d_out, int out_size, void* d_ws, size_t ws_size,
                              hipStream_t stream) {
    const float* z       = (const float*)d_in[0];
    const float* weights = (const float*)d_in[1];
    const float* means   = (const float*)d_in[2];
    const float* covs    = (const float*)d_in[3];
    const float* scale   = (const float*)d_in[4];
    float* out = (float*)d_out;

    int B = in_sizes[0] / (2 * K_KP);            // 4096
    int grid = (K_KP / TK) * (B / (TBS * NB));   // 16 * 32 = 512
    recovery_kernel<<<grid, 256, 0, stream>>>(z, weights, means, covs, scale, out, B);
}